// Round 1
// baseline (1968.578 us; speedup 1.0000x reference)
//
#include <hip/hip_runtime.h>
#include <stdint.h>

#define HEADS 8
#define SEQ 32
#define CDIM 1280
#define DH 160
#define NB 2048
#define MTOT (NB*SEQ)   // 65536

typedef __bf16 bf16x8 __attribute__((ext_vector_type(8)));
typedef float f32x4 __attribute__((ext_vector_type(4)));
typedef unsigned short u16;
typedef unsigned short u16x8 __attribute__((ext_vector_type(8)));

__device__ __forceinline__ u16 f2bf(float f) {
    unsigned int u = __builtin_bit_cast(unsigned int, f);
    return (u16)((u + 0x7fffu + ((u >> 16) & 1u)) >> 16);   // RNE
}

__device__ __forceinline__ f32x4 mfma16(bf16x8 a, bf16x8 b, f32x4 c) {
    return __builtin_amdgcn_mfma_f32_16x16x32_bf16(a, b, c, 0, 0, 0);
}

// async global->LDS, 16B per lane; LDS dest must be wave-uniform base (+lane*16 by HW)
__device__ __forceinline__ void gload_lds16(const u16* g, u16* l) {
    __builtin_amdgcn_global_load_lds(
        (__attribute__((address_space(1))) void*)(void*)(g),
        (__attribute__((address_space(3))) void*)(l), 16, 0, 0);
}

// ---------------- prep kernels ----------------

__global__ void pe_kernel(float* __restrict__ pe) {
    int idx = blockIdx.x * blockDim.x + threadIdx.x;   // 32*640 = 20480
    if (idx >= SEQ * (CDIM/2)) return;
    int s = idx / (CDIM/2), j = idx % (CDIM/2);
    float dv = expf((float)(2*j) * (-9.210340371976184f / (float)CDIM));
    float arg = (float)s * dv;
    pe[s*CDIM + 2*j]     = sinf(arg);
    pe[s*CDIM + 2*j + 1] = cosf(arg);
}

__global__ void wcvt_kernel(const float* __restrict__ a, const float* __restrict__ b,
                            const float* __restrict__ c, const float* __restrict__ d,
                            u16* __restrict__ oa, u16* __restrict__ ob,
                            u16* __restrict__ oc, u16* __restrict__ od) {
    int i = blockIdx.x * blockDim.x + threadIdx.x;
    if (i < CDIM*CDIM) {
        oa[i] = f2bf(a[i]); ob[i] = f2bf(b[i]);
        oc[i] = f2bf(c[i]); od[i] = f2bf(d[i]);
    }
}

__global__ void x_kernel(const float* __restrict__ hid, const float* __restrict__ pe,
                         u16* __restrict__ x) {
    size_t base = ((size_t)blockIdx.x * 256 + threadIdx.x) * 8;
    if (base >= (size_t)MTOT * CDIM) return;
    int col = (int)(base % CDIM);
    int s = (int)((base / CDIM) & (SEQ-1));
    const float4* h4 = (const float4*)(hid + base);
    float4 ha = h4[0], hb = h4[1];
    const float4* p4 = (const float4*)(pe + (size_t)s*CDIM + col);
    float4 pa = p4[0], pb = p4[1];
    u16x8 o;
    o[0]=f2bf(ha.x+pa.x); o[1]=f2bf(ha.y+pa.y); o[2]=f2bf(ha.z+pa.z); o[3]=f2bf(ha.w+pa.w);
    o[4]=f2bf(hb.x+pb.x); o[5]=f2bf(hb.y+pb.y); o[6]=f2bf(hb.z+pb.z); o[7]=f2bf(hb.w+pb.w);
    *(u16x8*)(x + base) = o;
}

// ---------------- GEMM: C[M,N] = A[M,K] @ Bt[N,K]^T (both row-major bf16) ----------------
// 128x128 tile, BK=32, 4 waves (2x2), 4x4 16x16x32 MFMA frags per wave. m97 structure.

template<int OUTF32>
__global__ __launch_bounds__(256) void gemm_bt(
    const u16* __restrict__ A, const u16* __restrict__ Bt,
    void* __restrict__ Cp, const float* __restrict__ bias, int ldc)
{
    __shared__ u16 Abuf[128*32];
    __shared__ u16 Bbuf[128*32];
    const int tid = threadIdx.x;
    const int wid = tid >> 6, lane = tid & 63;
    const int m0 = blockIdx.y << 7, n0 = blockIdx.x << 7;
    const int wm = wid >> 1, wn = wid & 1;

    // staging: 512 chunks of 16B per tile; chunk c -> row c>>2, kchunk c&3
    const u16* gA[2]; const u16* gB[2];
    u16* lA[2]; u16* lB[2];
    #pragma unroll
    for (int j = 0; j < 2; ++j) {
        int c = j*256 + tid;
        gA[j] = A + (size_t)(m0 + (c >> 2)) * CDIM + (size_t)((c & 3) * 8);
        gB[j] = Bt + (size_t)(n0 + (c >> 2)) * CDIM + (size_t)((c & 3) * 8);
        int ubase = (j*256 + (wid << 6)) << 3;   // element idx, wave-uniform
        lA[j] = Abuf + ubase;
        lB[j] = Bbuf + ubase;
    }

    const f32x4 zero4 = {0.0f, 0.0f, 0.0f, 0.0f};
    f32x4 acc[4][4];
    #pragma unroll
    for (int i = 0; i < 4; ++i)
        #pragma unroll
        for (int j = 0; j < 4; ++j) acc[i][j] = zero4;

    const int fr = lane & 15;
    const int kq = (lane >> 4) << 3;   // 0,8,16,24

    for (int ks = 0; ks < CDIM/32; ++ks) {
        __syncthreads();
        #pragma unroll
        for (int j = 0; j < 2; ++j) {
            gload_lds16(gA[j], lA[j]);
            gload_lds16(gB[j], lB[j]);
            gA[j] += 32; gB[j] += 32;
        }
        __syncthreads();
        bf16x8 af[4], bfr[4];
        #pragma unroll
        for (int i = 0; i < 4; ++i)
            af[i] = *(const bf16x8*)&Abuf[((wm<<6) + (i<<4) + fr)*32 + kq];
        #pragma unroll
        for (int j = 0; j < 4; ++j)
            bfr[j] = *(const bf16x8*)&Bbuf[((wn<<6) + (j<<4) + fr)*32 + kq];
        #pragma unroll
        for (int i = 0; i < 4; ++i)
            #pragma unroll
            for (int j = 0; j < 4; ++j)
                acc[i][j] = mfma16(af[i], bfr[j], acc[i][j]);
    }

    const int rq = (lane >> 4) << 2;
    #pragma unroll
    for (int i = 0; i < 4; ++i) {
        #pragma unroll
        for (int j = 0; j < 4; ++j) {
            #pragma unroll
            for (int t = 0; t < 4; ++t) {
                int row = m0 + (wm<<6) + (i<<4) + rq + t;
                int col = n0 + (wn<<6) + (j<<4) + fr;
                float v = acc[i][j][t];
                if (OUTF32) ((float*)Cp)[(size_t)row * ldc + col] = v + bias[col];
                else        ((u16*)Cp)[(size_t)row * ldc + col] = f2bf(v);
            }
        }
    }
}

// ---------------- attention: one block per (b,h) ----------------

__global__ __launch_bounds__(256) void attn_kernel(
    const u16* __restrict__ Q, const u16* __restrict__ K,
    const u16* __restrict__ V, u16* __restrict__ O)
{
    __shared__ u16 lq[SEQ*DH], lk[SEQ*DH], lv[SEQ*DH];
    __shared__ float sc[SEQ*SEQ];
    __shared__ u16 lp[SEQ*SEQ];

    const int blk = blockIdx.x;
    const int b = blk >> 3, h = blk & 7;
    const int tid = threadIdx.x, wid = tid >> 6, lane = tid & 63;
    const size_t base = (size_t)b * SEQ * CDIM + (size_t)h * DH;

    // load q,k,v tiles: 3 * 32 rows * 20 chunks of 16B
    for (int c = tid; c < 3*SEQ*20; c += 256) {
        int t = c / (SEQ*20), rem = c % (SEQ*20);
        int r = rem / 20, ch = rem % 20;
        const u16* src = (t == 0 ? Q : t == 1 ? K : V) + base + (size_t)r * CDIM + ch*8;
        u16x8 val = *(const u16x8*)src;
        u16* dst = (t == 0 ? lq : t == 1 ? lk : lv) + r*DH + ch*8;
        *(u16x8*)dst = val;
    }
    __syncthreads();

    const int fr = lane & 15;
    const int kq = (lane >> 4) << 3;
    const int rq = (lane >> 4) << 2;
    const f32x4 zero4 = {0.0f, 0.0f, 0.0f, 0.0f};

    // QK^T: wave -> 16x16 tile (fm,fn); K = 160 = 5 steps of 32
    {
        const int fm = wid >> 1, fn = wid & 1;
        f32x4 a = zero4;
        #pragma unroll
        for (int ks = 0; ks < 5; ++ks) {
            bf16x8 af  = *(const bf16x8*)&lq[((fm<<4) + fr)*DH + ks*32 + kq];
            bf16x8 bf_ = *(const bf16x8*)&lk[((fn<<4) + fr)*DH + ks*32 + kq];
            a = mfma16(af, bf_, a);
        }
        const float scale = 0.07905694150420949f;   // 1/sqrt(160)
        #pragma unroll
        for (int t = 0; t < 4; ++t)
            sc[((fm<<4) + rq + t)*SEQ + (fn<<4) + fr] = a[t] * scale;
    }
    __syncthreads();

    // softmax: wave handles 8 rows, 8 lanes per row, 4 elems per lane
    {
        int row = (wid << 3) + (lane >> 3), j8 = lane & 7;
        float4 vals = *(const float4*)&sc[row*SEQ + (j8 << 2)];
        float mx = fmaxf(fmaxf(vals.x, vals.y), fmaxf(vals.z, vals.w));
        #pragma unroll
        for (int m = 1; m < 8; m <<= 1) mx = fmaxf(mx, __shfl_xor(mx, m));
        float e0 = __expf(vals.x - mx), e1 = __expf(vals.y - mx),
              e2 = __expf(vals.z - mx), e3 = __expf(vals.w - mx);
        float sm = e0 + e1 + e2 + e3;
        #pragma unroll
        for (int m = 1; m < 8; m <<= 1) sm += __shfl_xor(sm, m);
        float inv = 1.0f / sm;
        lp[row*SEQ + (j8<<2) + 0] = f2bf(e0*inv);
        lp[row*SEQ + (j8<<2) + 1] = f2bf(e1*inv);
        lp[row*SEQ + (j8<<2) + 2] = f2bf(e2*inv);
        lp[row*SEQ + (j8<<2) + 3] = f2bf(e3*inv);
    }
    __syncthreads();

    // P @ V: out[32,160]; wave -> rows fm*16..+16, cols (wid&1)*80..+80 (5 frags)
    {
        const int fm = wid >> 1;
        const int cb = (wid & 1) * 80;
        bf16x8 pa = *(const bf16x8*)&lp[((fm<<4) + fr)*SEQ + kq];
        #pragma unroll
        for (int f = 0; f < 5; ++f) {
            int col = cb + (f << 4) + fr;
            u16x8 bb;
            #pragma unroll
            for (int j = 0; j < 8; ++j) bb[j] = lv[(kq + j)*DH + col];
            f32x4 acc = mfma16(pa, __builtin_bit_cast(bf16x8, bb), zero4);
            #pragma unroll
            for (int t = 0; t < 4; ++t) {
                int row = (fm << 4) + rq + t;
                O[base + (size_t)row*CDIM + col] = f2bf(acc[t]);
            }
        }
    }
}

// ---------------- launch ----------------
// ws layout (bytes):
//   [0, 163840)                      pe f32 [32][1280]
//   [163840, 13271040)               Wq,Wk,Wv,Wo bf16 (4 x 3276800)
//   [13271040, 181043200)            x bf16 [65536][1280]  (reused as attn_out)
//   [181043200, 348815360)           v bf16 [65536][1280]
// d_out (335MB) doubles as scratch for q (first half) and k (second half) as bf16.

extern "C" void kernel_launch(void* const* d_in, const int* in_sizes, int n_in,
                              void* d_out, int out_size, void* d_ws, size_t ws_size,
                              hipStream_t stream)
{
    (void)in_sizes; (void)n_in; (void)out_size; (void)ws_size;
    const float* hid = (const float*)d_in[0];
    const float* Wq  = (const float*)d_in[1];
    const float* Wk  = (const float*)d_in[2];
    const float* Wv  = (const float*)d_in[3];
    const float* Wo  = (const float*)d_in[4];
    const float* bo  = (const float*)d_in[5];

    char* ws = (char*)d_ws;
    float* pe = (float*)ws;
    u16* wq  = (u16*)(ws + 163840);
    u16* wk  = wq  + (size_t)CDIM*CDIM;
    u16* wvp = wk  + (size_t)CDIM*CDIM;
    u16* wo  = wvp + (size_t)CDIM*CDIM;
    u16* xb  = (u16*)(ws + 13271040);      // x, later attn_out
    u16* vb  = (u16*)(ws + 181043200);
    u16* qb  = (u16*)d_out;
    u16* kb  = qb + (size_t)MTOT*CDIM;

    pe_kernel<<<80, 256, 0, stream>>>(pe);
    wcvt_kernel<<<6400, 256, 0, stream>>>(Wq, Wk, Wv, Wo, wq, wk, wvp, wo);
    x_kernel<<<40960, 256, 0, stream>>>(hid, pe, xb);

    dim3 g(CDIM/128, MTOT/128);
    gemm_bt<0><<<g, 256, 0, stream>>>(xb, wq,  qb,    nullptr, CDIM);
    gemm_bt<0><<<g, 256, 0, stream>>>(xb, wk,  kb,    nullptr, CDIM);
    gemm_bt<0><<<g, 256, 0, stream>>>(xb, wvp, vb,    nullptr, CDIM);
    attn_kernel<<<NB*HEADS, 256, 0, stream>>>(qb, kb, vb, xb);
    gemm_bt<1><<<g, 256, 0, stream>>>(xb, wo, d_out, bo, CDIM);
}